// Round 11
// baseline (745.386 us; speedup 1.0000x reference)
//
#include <hip/hip_runtime.h>

#define NU  100000
#define NPR 20000
#define NN  120000   // NU + NPR
#define NE  1600000
#define NBLK 469     // ceil(NN/256)

typedef unsigned short ushrt;
typedef unsigned int   uint32;
typedef __attribute__((ext_vector_type(8))) short bf16x8;
typedef __attribute__((ext_vector_type(4))) float f32x4;

__device__ __forceinline__ float b2f(ushrt v){ union{uint32 i; float f;} c; c.i=((uint32)v)<<16; return c.f; }
__device__ __forceinline__ ushrt f2b(float f){ union{float ff; uint32 i;} c; c.ff=f; uint32 x=c.i; x += 0x7fffu + ((x>>16)&1u); return (ushrt)(x>>16); }
__device__ __forceinline__ int imin(int a,int b){ return a<b?a:b; }

__device__ __forceinline__ int esrc(const int* w, int e, int i64){ return i64 ? w[2*e]        : w[e]; }
__device__ __forceinline__ int edst(const int* w, int e, int i64){ return i64 ? w[2*NE + 2*e] : w[NE + e]; }
// non-temporal (no L2 allocate) variants for single-use streaming reads
__device__ __forceinline__ int esrc_nt(const int* w, int e, int i64){
  return i64 ? __builtin_nontemporal_load(w + 2*e) : __builtin_nontemporal_load(w + e);
}
__device__ __forceinline__ int edst_nt(const int* w, int e, int i64){
  return i64 ? __builtin_nontemporal_load(w + 2*NE + 2*e) : __builtin_nontemporal_load(w + NE + e);
}

// flags[0]=1 if float inputs are f32 (0 => bf16); flags[1]=1 if edges are int64
__global__ void detect_kernel(const void* xu, const void* ei, int* flags){
  if (blockIdx.x==0 && threadIdx.x==0){
    const ushrt* h = (const ushrt*)xu;
    int c=0;
    for (int i=0;i<512;i+=2){ int e=(h[i]>>7)&255; if (e>=100 && e<=140) c++; }
    flags[0] = (c < 128) ? 1 : 0;
    const int* wi = (const int*)ei;
    int allz = 1;
    for (int i=1;i<64;i+=2) if (wi[i]!=0) allz = 0;
    flags[1] = allz;
  }
}

// ---- consolidated weight staging: 19 arrays -> f32 wts in one launch ----
struct WJobs { const void* src[19]; int off[19]; int n[19]; int total; };
__global__ void __launch_bounds__(256) stage_w_all(float* __restrict__ wts, WJobs J, const int* __restrict__ flags){
  const int f32 = flags[0];
  for (int i = blockIdx.x*blockDim.x + threadIdx.x; i < J.total; i += gridDim.x*blockDim.x){
    int j = 0;
    while (j < 18 && i >= J.off[j] + J.n[j]) ++j;
    int k = i - J.off[j];
    wts[i] = f32 ? ((const float*)J.src[j])[k] : b2f(((const ushrt*)J.src[j])[k]);
  }
}

__global__ void __launch_bounds__(256) stage_bf16_kernel(ushrt* __restrict__ dst, const void* __restrict__ src,
                                                         int n, const int* __restrict__ flags){
  const int f32 = flags[0];
  for (int i = blockIdx.x*blockDim.x + threadIdx.x; i < n; i += gridDim.x*blockDim.x)
    dst[i] = f32 ? f2b(((const float*)src)[i]) : ((const ushrt*)src)[i];
}

// ---- consolidated weight prep: split f32 [K][N] -> transposed hi/lo bf16 [N][ldk], 10 jobs ----
struct PJobs { int src_off[10]; long long dh_off[10]; long long dl_off[10];
               int N[10]; int ldk[10]; int start[11]; };
__global__ void __launch_bounds__(256) prep_all(const float* __restrict__ wts, char* __restrict__ ws, PJobs P){
  int total = P.start[10];
  for (int i = blockIdx.x*blockDim.x + threadIdx.x; i < total; i += gridDim.x*blockDim.x){
    int j = 0;
    while (j < 9 && i >= P.start[j+1]) ++j;
    int idx = i - P.start[j];
    int N = P.N[j], ldk = P.ldk[j];
    int k = idx / N, n = idx - k*N;
    float w = wts[P.src_off[j] + idx];
    ushrt hi = f2b(w);
    float rem = w - b2f(hi);
    ((ushrt*)(ws + P.dh_off[j]))[(size_t)n*ldk + k] = hi;
    ((ushrt*)(ws + P.dl_off[j]))[(size_t)n*ldk + k] = f2b(rem);
  }
}

// ---------------- CSR build (XCD-sliced + nt streaming reads) ----------------
__global__ void __launch_bounds__(256) count_kernel(const int* __restrict__ ei, int* __restrict__ cnt,
                                                    const int* __restrict__ flags){
  const int i64 = flags[1];
  const int xcd = blockIdx.x & 7;
  const int sub = blockIdx.x >> 3;
  const int nsub = gridDim.x >> 3;
  for (int e = sub*256 + (int)threadIdx.x; e < NE; e += nsub*256){
    int d = edst_nt(ei,e,i64);
    if (d/15000 != xcd) continue;
    atomicAdd(&cnt[d], 1);
  }
}

__global__ void __launch_bounds__(256) scan_bsum_kernel(const int* __restrict__ cnt, int* __restrict__ bsum){
  __shared__ int sm[256];
  int i = blockIdx.x*256 + threadIdx.x;
  int v = (i < NN) ? cnt[i] : 0;
  sm[threadIdx.x] = v; __syncthreads();
  for (int off=128; off; off>>=1){
    if (threadIdx.x < off) sm[threadIdx.x] += sm[threadIdx.x+off];
    __syncthreads();
  }
  if (threadIdx.x == 0) bsum[blockIdx.x] = sm[0];
}

__global__ void __launch_bounds__(512) scan_boff_kernel(const int* __restrict__ bsum, int* __restrict__ boff){
  __shared__ int sm[512];
  int t = threadIdx.x;
  int v = (t < NBLK) ? bsum[t] : 0;
  sm[t] = v; __syncthreads();
  for (int off=1; off<512; off<<=1){
    int x = (t >= off) ? sm[t-off] : 0;
    __syncthreads();
    sm[t] += x;
    __syncthreads();
  }
  if (t < NBLK) boff[t] = sm[t] - v;   // exclusive
}

__global__ void __launch_bounds__(256) scan_final_kernel(const int* __restrict__ cnt, const int* __restrict__ boff,
                                                         int* __restrict__ row_start, int* __restrict__ cursor){
  __shared__ int sm[256];
  int t = threadIdx.x;
  int i = blockIdx.x*256 + t;
  int v = (i < NN) ? cnt[i] : 0;
  sm[t] = v; __syncthreads();
  for (int off=1; off<256; off<<=1){
    int x = (t >= off) ? sm[t-off] : 0;
    __syncthreads();
    sm[t] += x;
    __syncthreads();
  }
  int excl = boff[blockIdx.x] + sm[t] - v;
  if (i < NN){ row_start[i] = excl; cursor[i] = excl; }
  if (i == NN-1) row_start[NN] = excl + v;    // = NE
}

__global__ void __launch_bounds__(256) fill_kernel(const int* __restrict__ ei, const int* __restrict__ flags,
                                                   int* __restrict__ cursor, int* __restrict__ csr){
  const int i64 = flags[1];
  const int xcd = blockIdx.x & 7;
  const int sub = blockIdx.x >> 3;
  const int nsub = gridDim.x >> 3;
  for (int e = sub*256 + (int)threadIdx.x; e < NE; e += nsub*256){
    int d = edst_nt(ei,e,i64);
    if (d/15000 != xcd) continue;
    int s = esrc_nt(ei,e,i64);
    int pos = atomicAdd(&cursor[d], 1);
    csr[pos] = s;
  }
}

// ---------------- aggregation: 2 rows/wave (32 lanes x 8B), 4-edge unroll ----------------
__global__ void __launch_bounds__(256) aggregate_kernel(const ushrt* __restrict__ emb, const int* __restrict__ csr,
                                                        const int* __restrict__ rs, ushrt* __restrict__ aggr,
                                                        int r0, int nrows){
  const int l5 = threadIdx.x & 31;
  const int row = blockIdx.x*8 + (threadIdx.x >> 5);
  if (row >= nrows) return;
  const int r = r0 + row;
  const int j0 = rs[r], j1 = rs[r+1];
  float a0=0.f, a1=0.f, a2=0.f, a3=0.f;
  int j = j0;
  for (; j+3 < j1; j += 4){
    int s0 = csr[j], s1 = csr[j+1], s2 = csr[j+2], s3 = csr[j+3];
    uint2 u0 = *(const uint2*)(emb + (size_t)s0*128 + l5*4);
    uint2 u1 = *(const uint2*)(emb + (size_t)s1*128 + l5*4);
    uint2 u2 = *(const uint2*)(emb + (size_t)s2*128 + l5*4);
    uint2 u3 = *(const uint2*)(emb + (size_t)s3*128 + l5*4);
    a0 += (b2f((ushrt)u0.x) + b2f((ushrt)u1.x)) + (b2f((ushrt)u2.x) + b2f((ushrt)u3.x));
    a1 += (b2f((ushrt)(u0.x>>16)) + b2f((ushrt)(u1.x>>16))) + (b2f((ushrt)(u2.x>>16)) + b2f((ushrt)(u3.x>>16)));
    a2 += (b2f((ushrt)u0.y) + b2f((ushrt)u1.y)) + (b2f((ushrt)u2.y) + b2f((ushrt)u3.y));
    a3 += (b2f((ushrt)(u0.y>>16)) + b2f((ushrt)(u1.y>>16))) + (b2f((ushrt)(u2.y>>16)) + b2f((ushrt)(u3.y>>16)));
  }
  for (; j < j1; ++j){
    int s0 = csr[j];
    uint2 u = *(const uint2*)(emb + (size_t)s0*128 + l5*4);
    a0 += b2f((ushrt)u.x); a1 += b2f((ushrt)(u.x>>16));
    a2 += b2f((ushrt)u.y); a3 += b2f((ushrt)(u.y>>16));
  }
  float inv = 1.f / fmaxf((float)(j1 - j0), 1.f);
  uint2 o;
  o.x = (uint32)f2b(a0*inv) | ((uint32)f2b(a1*inv) << 16);
  o.y = (uint32)f2b(a2*inv) | ((uint32)f2b(a3*inv) << 16);
  *(uint2*)(aggr + (size_t)row*128 + l5*4) = o;
}

// ---------------- MFMA dense: LDS-staged B, 256 rows/block (4 waves x RT=4) ----------------
__device__ __forceinline__ void stage_B(const ushrt* __restrict__ WhT, const ushrt* __restrict__ WlT,
                                        int ldk, int koff, bf16x8 (&ldsb)[2][32][16], int tid){
  const int h = tid >> 7, n = tid & 127;
  const ushrt* src = (h ? WlT : WhT) + (size_t)n*ldk + koff;
#pragma unroll
  for (int kg=0; kg<4; ++kg)
    ldsb[h][(n>>4)*4 + kg][n&15] = *(const bf16x8*)(src + kg*8);
}

__device__ __forceinline__ void compute_phase(f32x4 (&acc)[4][8], const ushrt* __restrict__ X, int ldx,
                                              const int* ar, int xkoff, bf16x8 (&ldsb)[2][32][16],
                                              int kg, int c0){
  bf16x8 a[4];
#pragma unroll
  for (int rt=0; rt<4; ++rt) a[rt] = *(const bf16x8*)(X + (size_t)ar[rt]*ldx + xkoff + kg*8);
#pragma unroll
  for (int t=0; t<8; ++t){
    bf16x8 bh = ldsb[0][t*4+kg][c0];
#pragma unroll
    for (int rt=0; rt<4; ++rt)
      acc[rt][t] = __builtin_amdgcn_mfma_f32_16x16x32_bf16(a[rt], bh, acc[rt][t], 0,0,0);
  }
#pragma unroll
  for (int t=0; t<8; ++t){
    bf16x8 bl = ldsb[1][t*4+kg][c0];
#pragma unroll
    for (int rt=0; rt<4; ++rt)
      acc[rt][t] = __builtin_amdgcn_mfma_f32_16x16x32_bf16(a[rt], bl, acc[rt][t], 0,0,0);
  }
}

template<bool RELU>
__device__ __forceinline__ void store_tile(f32x4 (&acc)[8], const float* __restrict__ bias,
                                           ushrt* __restrict__ Y, int tilebase, int rows, int lane){
  const int c0 = lane & 15, g = lane >> 4;
  if (tilebase >= rows) return;
#pragma unroll
  for (int t=0;t<8;++t){
    int c = t*16 + c0;
    float b = bias[c];
#pragma unroll
    for (int j=0;j<4;++j){
      int m = tilebase + g*4 + j;
      if (m < rows){
        float v = acc[t][j] + b;
        if (RELU) v = fmaxf(v, 0.f);
        Y[(size_t)m*128 + c] = f2b(v);
      }
    }
  }
}

template<int K, bool RELU>
__global__ void __launch_bounds__(256,2) mfma_lds_lin(const ushrt* __restrict__ X,
    const ushrt* __restrict__ WhT, const ushrt* __restrict__ WlT,
    const float* __restrict__ bias, ushrt* __restrict__ Y, int rows){
  __shared__ bf16x8 ldsb[2][32][16];
  const int tid = threadIdx.x, lane = tid & 63;
  const int c0 = lane & 15, kg = lane >> 4;
  const int rb = blockIdx.x*256 + (tid>>6)*64;
  int ar[4];
#pragma unroll
  for (int rt=0; rt<4; ++rt) ar[rt] = imin(rb + rt*16 + c0, rows-1);
  f32x4 acc[4][8];
#pragma unroll
  for (int rt=0; rt<4; ++rt)
#pragma unroll
    for (int t=0; t<8; ++t) acc[rt][t] = (f32x4){0.f,0.f,0.f,0.f};
  for (int ks=0; ks<K; ks+=32){
    stage_B(WhT, WlT, K, ks, ldsb, tid);
    __syncthreads();
    compute_phase(acc, X, K, ar, ks, ldsb, kg, c0);
    __syncthreads();
  }
#pragma unroll
  for (int rt=0; rt<4; ++rt) store_tile<RELU>(acc[rt], bias, Y, rb + rt*16, rows, lane);
}

__global__ void __launch_bounds__(256,2) mfma_lds_sage(const ushrt* __restrict__ aggr,
    const ushrt* __restrict__ emb,
    const ushrt* __restrict__ wha, const ushrt* __restrict__ wla,
    const ushrt* __restrict__ whr, const ushrt* __restrict__ wlr,
    const float* __restrict__ bias, ushrt* __restrict__ Y, int r0, int nrows){
  __shared__ bf16x8 ldsb[2][32][16];
  const int tid = threadIdx.x, lane = tid & 63;
  const int c0 = lane & 15, kg = lane >> 4;
  const int rb = blockIdx.x*256 + (tid>>6)*64;
  int ar[4];
#pragma unroll
  for (int rt=0; rt<4; ++rt) ar[rt] = imin(rb + rt*16 + c0, nrows-1);
  f32x4 acc[4][8];
#pragma unroll
  for (int rt=0; rt<4; ++rt)
#pragma unroll
    for (int t=0; t<8; ++t) acc[rt][t] = (f32x4){0.f,0.f,0.f,0.f};
  for (int ks=0; ks<128; ks+=32){
    stage_B(wha, wla, 128, ks, ldsb, tid);
    __syncthreads();
    compute_phase(acc, aggr, 128, ar, ks, ldsb, kg, c0);
    __syncthreads();
  }
  const ushrt* embr = emb + (size_t)r0*128;
  for (int ks=0; ks<128; ks+=32){
    stage_B(whr, wlr, 128, ks, ldsb, tid);
    __syncthreads();
    compute_phase(acc, embr, 128, ar, ks, ldsb, kg, c0);
    __syncthreads();
  }
#pragma unroll
  for (int rt=0; rt<4; ++rt) store_tile<true>(acc[rt], bias, Y, rb + rt*16, nrows, lane);
}

__global__ void __launch_bounds__(256,2) mfma_lds_hc1(const ushrt* __restrict__ e0,
    const ushrt* __restrict__ e1, const ushrt* __restrict__ e2,
    const ushrt* __restrict__ WhT, const ushrt* __restrict__ WlT,
    const float* __restrict__ bias, ushrt* __restrict__ Y, int rows){
  __shared__ bf16x8 ldsb[2][32][16];
  const int tid = threadIdx.x, lane = tid & 63;
  const int c0 = lane & 15, kg = lane >> 4;
  const int rb = blockIdx.x*256 + (tid>>6)*64;
  int ar[4];
#pragma unroll
  for (int rt=0; rt<4; ++rt) ar[rt] = imin(rb + rt*16 + c0, rows-1);
  f32x4 acc[4][8];
#pragma unroll
  for (int rt=0; rt<4; ++rt)
#pragma unroll
    for (int t=0; t<8; ++t) acc[rt][t] = (f32x4){0.f,0.f,0.f,0.f};
  const ushrt* Xs[3] = { e0, e1, e2 };
#pragma unroll
  for (int seg=0; seg<3; ++seg){
    for (int ks=0; ks<128; ks+=32){
      stage_B(WhT, WlT, 384, seg*128 + ks, ldsb, tid);
      __syncthreads();
      compute_phase(acc, Xs[seg], 128, ar, ks, ldsb, kg, c0);
      __syncthreads();
    }
  }
#pragma unroll
  for (int rt=0; rt<4; ++rt) store_tile<true>(acc[rt], bias, Y, rb + rt*16, rows, lane);
}

// head fused: cols 0..63 -> h_t0 (hctl), 64..127 -> h_t1 (htr); writes h blocks AND scalar outs
__global__ void __launch_bounds__(256,2) mfma_lds_head(const ushrt* __restrict__ X,
    const ushrt* __restrict__ WhT, const ushrt* __restrict__ WlT,
    const float* __restrict__ bC, const float* __restrict__ bT,
    const float* __restrict__ ocW, const float* __restrict__ ocB,
    const float* __restrict__ otW, const float* __restrict__ otB,
    float* __restrict__ out, int rows){
  __shared__ bf16x8 ldsb[2][32][16];
  const int tid = threadIdx.x, lane = tid & 63;
  const int c0 = lane & 15, kg = lane >> 4, g = lane >> 4;
  const int rb = blockIdx.x*256 + (tid>>6)*64;
  int ar[4];
#pragma unroll
  for (int rt=0; rt<4; ++rt) ar[rt] = imin(rb + rt*16 + c0, rows-1);
  f32x4 acc[4][8];
#pragma unroll
  for (int rt=0; rt<4; ++rt)
#pragma unroll
    for (int t=0; t<8; ++t) acc[rt][t] = (f32x4){0.f,0.f,0.f,0.f};
  for (int ks=0; ks<128; ks+=32){
    stage_B(WhT, WlT, 128, ks, ldsb, tid);
    __syncthreads();
    compute_phase(acc, X, 128, ar, ks, ldsb, kg, c0);
    __syncthreads();
  }
  float* ht1 = out + 2*(size_t)NU;
  float* ht0 = out + 2*(size_t)NU + 64*(size_t)NU;
  const float ocb = ocB[0], otb = otB[0];
#pragma unroll
  for (int rt=0; rt<4; ++rt){
    int tb = rb + rt*16;
    if (tb >= rows) break;
    float p[4] = {0.f,0.f,0.f,0.f}, q[4] = {0.f,0.f,0.f,0.f};
#pragma unroll
    for (int t=0; t<8; ++t){
      int c = t*16 + c0;
      bool ctl = (c < 64);
      int cc = ctl ? c : c - 64;
      float b = ctl ? bC[cc] : bT[cc];
      float wsc = ctl ? ocW[cc] : otW[cc];
      float* dst = ctl ? ht0 : ht1;
#pragma unroll
      for (int j=0; j<4; ++j){
        int m = tb + g*4 + j;
        float v = fmaxf(acc[rt][t][j] + b, 0.f);
        if (m < rows) dst[(size_t)m*64 + cc] = v;
        if (ctl) p[j] += v*wsc; else q[j] += v*wsc;
      }
    }
#pragma unroll
    for (int off=1; off<16; off<<=1){
#pragma unroll
      for (int j=0; j<4; ++j){ p[j] += __shfl_xor(p[j], off); q[j] += __shfl_xor(q[j], off); }
    }
    if (c0 == 0){
#pragma unroll
      for (int j=0; j<4; ++j){
        int m = tb + g*4 + j;
        if (m < rows){
          out[m]      = fmaxf(q[j] + otb, 0.f);   // out_t1
          out[NU + m] = fmaxf(p[j] + ocb, 0.f);   // out_t0
        }
      }
    }
  }
}

__global__ void sentinel_kernel(float* out, int n, float val){
  for (int i = blockIdx.x*blockDim.x + threadIdx.x; i < n; i += gridDim.x*blockDim.x) out[i] = val;
}

extern "C" void kernel_launch(void* const* d_in, const int* in_sizes, int n_in,
                              void* d_out, int out_size, void* d_ws, size_t ws_size,
                              hipStream_t stream){
  char* w = (char*)d_ws;
  float* out = (float*)d_out;

  size_t wo[22]; size_t acc=0;
  for (int i=3;i<=21;i++){ wo[i]=acc; acc += (size_t)in_sizes[i]; }

  size_t cur=0;
  auto alloc=[&](size_t b){ size_t r=cur; cur=(cur+b+255)&~(size_t)255; return r; };
  size_t o_flags = alloc(256);
  size_t o_wts   = alloc(acc*4);
  size_t o_cnt   = alloc((size_t)NN*4);
  size_t o_rs    = alloc(((size_t)NN+1)*4);
  size_t o_cur   = alloc((size_t)NN*4);
  size_t o_bsum  = alloc((size_t)NBLK*4);
  size_t o_boff  = alloc((size_t)NBLK*4);
  size_t o_csr   = alloc((size_t)NE*4);
  size_t o_xub   = alloc((size_t)NU*128*2);
  size_t o_xpb   = alloc((size_t)NPR*64*2);
  size_t o_ueh = alloc(16384*2), o_uel = alloc(16384*2);
  size_t o_ieh = alloc(8192*2),  o_iel = alloc(8192*2);
  size_t o_wl0h= alloc(16384*2), o_wl0l= alloc(16384*2);
  size_t o_wr0h= alloc(16384*2), o_wr0l= alloc(16384*2);
  size_t o_wl1h= alloc(16384*2), o_wl1l= alloc(16384*2);
  size_t o_wr1h= alloc(16384*2), o_wr1l= alloc(16384*2);
  size_t o_hc1h= alloc(49152*2), o_hc1l= alloc(49152*2);
  size_t o_hc2h= alloc(16384*2), o_hc2l= alloc(16384*2);
  size_t o_hdh = alloc(16384*2), o_hdl = alloc(16384*2);
  size_t o_e0  = alloc((size_t)NN*128*2);
  size_t o_e1  = alloc((size_t)NN*128*2);
  size_t o_e2  = alloc((size_t)NU*128*2);
  size_t fixed = cur;

  const long long CRMIN = 4096;
  if (ws_size < fixed + (size_t)CRMIN*256 + 4096){
    sentinel_kernel<<<2048,256,0,stream>>>(out, out_size, 1024.0f + (float)(ws_size>>20));
    return;
  }
  long long CR = (long long)((ws_size - fixed)/256); if (CR > NN) CR = NN;
  size_t o_aggr = alloc((size_t)CR*256);

  int*   flags=(int*)(w+o_flags);
  float* wts  =(float*)(w+o_wts);
  int*   cnt  =(int*)(w+o_cnt);
  int*   rs   =(int*)(w+o_rs);
  int*   curp =(int*)(w+o_cur);
  int*   bsum =(int*)(w+o_bsum);
  int*   boff =(int*)(w+o_boff);
  int*   csr  =(int*)(w+o_csr);
  ushrt* xu_b =(ushrt*)(w+o_xub);
  ushrt* xp_b =(ushrt*)(w+o_xpb);
  ushrt* emb0 =(ushrt*)(w+o_e0);
  ushrt* emb1 =(ushrt*)(w+o_e1);
  ushrt* emb2 =(ushrt*)(w+o_e2);
  ushrt* aggrb=(ushrt*)(w+o_aggr);
  const int* ei=(const int*)d_in[2];

  detect_kernel<<<1,64,0,stream>>>(d_in[0], d_in[2], flags);

  // consolidated weight staging (19 arrays, 1 launch)
  WJobs wj;
  for (int i=3;i<=21;i++){ wj.src[i-3]=d_in[i]; wj.off[i-3]=(int)wo[i]; wj.n[i-3]=in_sizes[i]; }
  wj.total = (int)acc;
  stage_w_all<<<256,256,0,stream>>>(wts, wj, flags);
  stage_bf16_kernel<<<4096,256,0,stream>>>(xu_b, d_in[0], NU*128, flags);
  stage_bf16_kernel<<<1024,256,0,stream>>>(xp_b, d_in[1], NPR*64, flags);

  // consolidated weight prep (10 jobs, 1 launch)
  PJobs pj;
  {
    int   so[10] = {(int)wo[3],(int)wo[5],(int)wo[7],(int)wo[7]+16384,(int)wo[9],(int)wo[9]+16384,
                    (int)wo[10],(int)wo[12],(int)wo[14],(int)wo[16]};
    size_t dh[10]= {o_ueh,o_ieh,o_wl0h,o_wl1h,o_wr0h,o_wr1h,o_hc1h,o_hc2h,o_hdh,o_hdh+16384};
    size_t dl[10]= {o_uel,o_iel,o_wl0l,o_wl1l,o_wr0l,o_wr1l,o_hc1l,o_hc2l,o_hdl,o_hdl+16384};
    int   Nn[10] = {128,128,128,128,128,128,128,128,64,64};
    int   Kk[10] = {128,64,128,128,128,128,384,128,128,128};
    int   ld[10] = {128,64,128,128,128,128,384,128,128,128};
    int st = 0;
    for (int j=0;j<10;++j){
      pj.src_off[j]=so[j]; pj.dh_off[j]=(long long)dh[j]; pj.dl_off[j]=(long long)dl[j];
      pj.N[j]=Nn[j]; pj.ldk[j]=ld[j]; pj.start[j]=st; st += Kk[j]*Nn[j];
    }
    pj.start[10]=st;
  }
  prep_all<<<512,256,0,stream>>>(wts, w, pj);

  // CSR build (XCD-sliced count/fill, nt streaming reads)
  hipMemsetAsync(cnt, 0, (size_t)NN*4, stream);
  count_kernel<<<2048, 256, 0, stream>>>(ei, cnt, flags);
  scan_bsum_kernel<<<NBLK, 256, 0, stream>>>(cnt, bsum);
  scan_boff_kernel<<<1, 512, 0, stream>>>(bsum, boff);
  scan_final_kernel<<<NBLK, 256, 0, stream>>>(cnt, boff, rs, curp);
  fill_kernel<<<2048, 256, 0, stream>>>(ei, flags, curp, csr);

  // encoders
  mfma_lds_lin<128,false><<<(NU+255)/256, 256, 0, stream>>>(xu_b,
      (ushrt*)(w+o_ueh), (ushrt*)(w+o_uel), wts+wo[4], emb0, NU);
  mfma_lds_lin<64,false><<<(NPR+255)/256, 256, 0, stream>>>(xp_b,
      (ushrt*)(w+o_ieh), (ushrt*)(w+o_iel), wts+wo[6], emb0 + (size_t)NU*128, NPR);

  // layer 1 (all NN rows)
  for (long long r0=0; r0<NN; r0+=CR){
    long long nr = (NN-r0 < CR) ? (NN-r0) : CR;
    aggregate_kernel<<<(int)((nr+7)/8), 256, 0, stream>>>(emb0, csr, rs, aggrb, (int)r0, (int)nr);
    mfma_lds_sage<<<(int)((nr+255)/256), 256, 0, stream>>>(aggrb, emb0,
        (ushrt*)(w+o_wl0h), (ushrt*)(w+o_wl0l), (ushrt*)(w+o_wr0h), (ushrt*)(w+o_wr0l),
        wts+wo[8], emb1 + (size_t)r0*128, (int)r0, (int)nr);
  }
  // layer 2 (user rows only)
  for (long long r0=0; r0<NU; r0+=CR){
    long long nr = (NU-r0 < CR) ? (NU-r0) : CR;
    aggregate_kernel<<<(int)((nr+7)/8), 256, 0, stream>>>(emb1, csr, rs, aggrb, (int)r0, (int)nr);
    mfma_lds_sage<<<(int)((nr+255)/256), 256, 0, stream>>>(aggrb, emb1,
        (ushrt*)(w+o_wl1h), (ushrt*)(w+o_wl1l), (ushrt*)(w+o_wr1h), (ushrt*)(w+o_wr1l),
        wts+wo[8]+128, emb2 + (size_t)r0*128, (int)r0, (int)nr);
  }

  // MLP head
  mfma_lds_hc1<<<(NU+255)/256, 256, 0, stream>>>(emb0, emb1, emb2,
      (ushrt*)(w+o_hc1h), (ushrt*)(w+o_hc1l), wts+wo[11], emb0 /*hid1 alias*/, NU);
  mfma_lds_lin<128,true><<<(NU+255)/256, 256, 0, stream>>>(emb0,
      (ushrt*)(w+o_hc2h), (ushrt*)(w+o_hc2l), wts+wo[13], emb1 /*hid2 alias*/, NU);
  mfma_lds_head<<<(NU+255)/256, 256, 0, stream>>>(emb1,
      (ushrt*)(w+o_hdh), (ushrt*)(w+o_hdl), wts+wo[15], wts+wo[17],
      wts+wo[18], wts+wo[19], wts+wo[20], wts+wo[21], out, NU);
}